// Round 1
// baseline (707.916 us; speedup 1.0000x reference)
//
#include <hip/hip_runtime.h>
#include <math.h>

#define IC 64
#define OC 128
#define HW_ 64
#define OHW 62
#define BATCH 32
#define Y_SIZE (BATCH*OC*OHW*OHW)   /* 15740928 */
#define UPD_SIZE (OC*IC*9)          /* 73728 */

// ---------------- K1: weight norm + transpose to [c*9+ij][k] ----------------
__global__ void wnorm_kernel(const float* __restrict__ w, float* __restrict__ wT) {
    int k = blockIdx.x;      // 0..127
    int c = threadIdx.x;     // 0..63 (one wave)
    const float* wp = w + ((size_t)k*IC + c)*9;
    float v[9]; float s = 0.f;
#pragma unroll
    for (int t = 0; t < 9; ++t) { v[t] = wp[t]; s += v[t]*v[t]; }
#pragma unroll
    for (int off = 32; off > 0; off >>= 1) s += __shfl_down(s, off);
    s = __shfl(s, 0);
    float nrm = sqrtf(s);
    if (nrm == 0.f) nrm = 1.f;
#pragma unroll
    for (int t = 0; t < 9; ++t) wT[(c*9 + t)*OC + k] = v[t] / nrm;
}

// ---------------- K2: conv + bias + per-row argmax ----------------
// grid (62 oh, 32 b), 256 threads. Each thread: 8k x 4ow register tile.
__global__ __launch_bounds__(256, 2) void conv_kernel(
    const float* __restrict__ x, const float* __restrict__ wT,
    const float* __restrict__ bias, float* __restrict__ y,
    int* __restrict__ winners)
{
    __shared__ float xs[IC][3][68];      // 52224 B, cols 64..67 zero pad
    __shared__ float red_v[OHW][17];
    __shared__ int   red_i[OHW][17];

    const int oh = blockIdx.x;
    const int b  = blockIdx.y;
    const int tid = threadIdx.x;

    // stage x[b, :, oh..oh+2, :] -> LDS (float4, coalesced)
    const float* xb = x + ((size_t)b*IC)*4096 + oh*64;
    for (int t = tid; t < 3072; t += 256) {
        int flat = t*4;
        int c = flat/192, rem = flat%192;
        int i = rem/64,  w = rem%64;
        float4 v = *(const float4*)(xb + (size_t)c*4096 + i*64 + w);
        *(float4*)(&xs[c][i][w]) = v;
    }
    if (tid < 192) {
        int c = tid/3, i = tid%3;
        *(float4*)(&xs[c][i][64]) = make_float4(0.f,0.f,0.f,0.f);
    }
    __syncthreads();

    const int owq = tid & 15, kg = tid >> 4;
    const int ow0 = owq*4,  k0 = kg*8;

    float acc[8][4];
#pragma unroll
    for (int a = 0; a < 8; ++a)
#pragma unroll
        for (int m = 0; m < 4; ++m) acc[a][m] = 0.f;

    const float* wbase = wT + k0;
    for (int c = 0; c < IC; ++c) {
#pragma unroll
        for (int i = 0; i < 3; ++i) {
            const float* xr = &xs[c][i][ow0];
            float xv[6];
#pragma unroll
            for (int t = 0; t < 6; ++t) xv[t] = xr[t];
            const float* wr = wbase + (c*9 + i*3)*OC;
#pragma unroll
            for (int j = 0; j < 3; ++j) {
                float4 wa = *(const float4*)(wr + j*OC);
                float4 wb = *(const float4*)(wr + j*OC + 4);
                float wv[8] = {wa.x,wa.y,wa.z,wa.w, wb.x,wb.y,wb.z,wb.w};
#pragma unroll
                for (int kk = 0; kk < 8; ++kk)
#pragma unroll
                    for (int m = 0; m < 4; ++m)
                        acc[kk][m] += wv[kk] * xv[j+m];
            }
        }
    }

    // bias + store y + per-thread argmax over its 8 k
    float bvals[8];
#pragma unroll
    for (int kk = 0; kk < 8; ++kk) bvals[kk] = bias[k0+kk];
    float* yb = y + (((size_t)b*OC + k0)*OHW + oh)*OHW;
#pragma unroll
    for (int m = 0; m < 4; ++m) {
        int ow = ow0 + m;
        if (ow < OHW) {
            float vmax = -3.4e38f; int imax = 0;
#pragma unroll
            for (int kk = 0; kk < 8; ++kk) {
                float v = acc[kk][m] + bvals[kk];
                yb[(size_t)kk*OHW*OHW + ow] = v;
                if (v > vmax) { vmax = v; imax = k0 + kk; }
            }
            red_v[ow][kg] = vmax; red_i[ow][kg] = imax;
        }
    }
    __syncthreads();

    if (tid < OHW) {
        float best = red_v[tid][0]; int bk = red_i[tid][0];
#pragma unroll
        for (int g2 = 1; g2 < 16; ++g2) {
            float v = red_v[tid][g2];
            if (v > best) { best = v; bk = red_i[tid][g2]; }  // strict >: first-max tie-break
        }
        winners[((size_t)b*OHW + oh)*OHW + tid] = bk;
    }
}

// ---------------- K3: Hebbian partial accumulation ----------------
// grid (c=64, g=4). Each block: 8 batches, LDS accumulator [128k][9] via atomics.
__global__ void hebb_kernel(const float* __restrict__ x,
                            const int* __restrict__ winners,
                            float* __restrict__ part)
{
    __shared__ float hl[OC*9];     // 4608 B
    __shared__ float xch[4096];    // 16384 B, one channel image
    const int c = blockIdx.x, g = blockIdx.y;
    const int tid = threadIdx.x;

    for (int t = tid; t < OC*9; t += 256) hl[t] = 0.f;

    for (int bb = 0; bb < 8; ++bb) {
        int b = g*8 + bb;
        __syncthreads();   // prior users of xch done (also covers hl init)
        const float4* src = (const float4*)(x + ((size_t)b*IC + c)*4096);
        for (int t = tid; t < 1024; t += 256) ((float4*)xch)[t] = src[t];
        __syncthreads();
        for (int loc = tid; loc < OHW*OHW; loc += 256) {
            int ohh = loc / OHW;
            int oww = loc - ohh*OHW;
            int k = winners[((size_t)b*OHW + ohh)*OHW + oww];
            const float* xp = xch + ohh*64 + oww;
            float* hp = hl + k*9;
#pragma unroll
            for (int i = 0; i < 3; ++i)
#pragma unroll
                for (int j = 0; j < 3; ++j)
                    atomicAdd(&hp[i*3+j], xp[i*64+j]);
        }
    }
    __syncthreads();
    float* dst = part + ((size_t)c*4 + g)*(OC*9);
    for (int t = tid; t < OC*9; t += 256) dst[t] = hl[t];
}

// ---------------- K4: reduce partials + scale ----------------
__global__ void final_kernel(const float* __restrict__ part, float* __restrict__ upd) {
    int idx = blockIdx.x*256 + threadIdx.x;
    if (idx >= UPD_SIZE) return;
    int k  = idx / 576;
    int r  = idx - k*576;
    int c  = r / 9;
    int ij = r - c*9;
    float s = 0.f;
#pragma unroll
    for (int g = 0; g < 4; ++g) s += part[(((size_t)c*4 + g)*OC + k)*9 + ij];
    upd[idx] = s / 123008.0f;
}

extern "C" void kernel_launch(void* const* d_in, const int* in_sizes, int n_in,
                              void* d_out, int out_size, void* d_ws, size_t ws_size,
                              hipStream_t stream) {
    const float* x    = (const float*)d_in[0];
    const float* w    = (const float*)d_in[1];
    const float* bias = (const float*)d_in[2];
    float* out = (float*)d_out;
    float* y   = out;
    float* upd = out + Y_SIZE;

    // ws layout: wT (294912 B) | winners (492032 B) | part (1179648 B)  ~1.97 MB
    float* wT      = (float*)d_ws;
    int*   winners = (int*)((char*)d_ws + (size_t)UPD_SIZE*4);
    float* part    = (float*)((char*)d_ws + (size_t)UPD_SIZE*4 + (size_t)BATCH*OHW*OHW*4);

    wnorm_kernel<<<OC, IC, 0, stream>>>(w, wT);
    conv_kernel<<<dim3(OHW, BATCH), 256, 0, stream>>>(x, wT, bias, y, winners);
    hebb_kernel<<<dim3(IC, 4), 256, 0, stream>>>(x, winners, part);
    final_kernel<<<(UPD_SIZE + 255)/256, 256, 0, stream>>>(part, upd);
}